// Round 1
// baseline (4119.032 us; speedup 1.0000x reference)
//
#include <hip/hip_runtime.h>
#include <cmath>

#define SEQ 2048
#define DIM 512
#define FDIM 512
#define HDIM 2048
#define VOCAB 32000
#define NLAYER 4
#define LNEPS 1e-5f

// ---------------- GEMM NN: C[M,N] = A[M,K] @ B[K,N] + bias ----------------
// 64x64 tile, BK=16, 256 threads, 4x4 micro-tile per thread.
__global__ __launch_bounds__(256) void gemm_nn_k(
    const float* __restrict__ A, const float* __restrict__ B,
    const float* __restrict__ bias, float* __restrict__ C,
    int M, int N, int K)
{
    __shared__ float As[16][64];   // As[k][m]
    __shared__ float Bs[16][64];   // Bs[k][n]
    const int tid = threadIdx.x;
    const int tx = tid & 15, ty = tid >> 4;
    const int bx = blockIdx.x, by = blockIdx.y;
    const int arow = tid >> 2;          // 0..63 (m within tile)
    const int acol = (tid & 3) << 2;    // 0,4,8,12 (k within tile)
    const int brow = tid >> 4;          // 0..15 (k within tile)
    const int bcol = (tid & 15) << 2;   // 0..60 (n within tile)
    const float* Ap = A + (size_t)((by << 6) + arow) * K + acol;
    const float* Bp = B + (size_t)brow * N + (size_t)(bx << 6) + bcol;
    float acc[4][4] = {};
    for (int k0 = 0; k0 < K; k0 += 16) {
        float4 av = *(const float4*)Ap;
        float4 bv = *(const float4*)Bp;
        As[acol + 0][arow] = av.x;
        As[acol + 1][arow] = av.y;
        As[acol + 2][arow] = av.z;
        As[acol + 3][arow] = av.w;
        *(float4*)&Bs[brow][bcol] = bv;
        __syncthreads();
#pragma unroll
        for (int kk = 0; kk < 16; kk++) {
            float4 a = *(const float4*)&As[kk][ty << 2];
            float4 b = *(const float4*)&Bs[kk][tx << 2];
            acc[0][0] += a.x * b.x; acc[0][1] += a.x * b.y; acc[0][2] += a.x * b.z; acc[0][3] += a.x * b.w;
            acc[1][0] += a.y * b.x; acc[1][1] += a.y * b.y; acc[1][2] += a.y * b.z; acc[1][3] += a.y * b.w;
            acc[2][0] += a.z * b.x; acc[2][1] += a.z * b.y; acc[2][2] += a.z * b.z; acc[2][3] += a.z * b.w;
            acc[3][0] += a.w * b.x; acc[3][1] += a.w * b.y; acc[3][2] += a.w * b.z; acc[3][3] += a.w * b.w;
        }
        __syncthreads();
        Ap += 16;
        Bp += (size_t)16 * N;
    }
    const int ccol = (bx << 6) + (tx << 2);
    float4 bb = make_float4(0.f, 0.f, 0.f, 0.f);
    if (bias) bb = *(const float4*)&bias[ccol];
#pragma unroll
    for (int i = 0; i < 4; i++) {
        const int row = (by << 6) + (ty << 2) + i;
        float4 o;
        o.x = acc[i][0] + bb.x;
        o.y = acc[i][1] + bb.y;
        o.z = acc[i][2] + bb.z;
        o.w = acc[i][3] + bb.w;
        *(float4*)&C[(size_t)row * N + ccol] = o;
    }
}

// ---------------- GEMM NT: C[M,N] = scale * A[M,K] @ B[N,K]^T -------------
__global__ __launch_bounds__(256) void gemm_nt_k(
    const float* __restrict__ A, const float* __restrict__ B,
    float* __restrict__ C, int M, int N, int K, float scale)
{
    __shared__ float As[16][64];
    __shared__ float Bs[16][64];
    const int tid = threadIdx.x;
    const int tx = tid & 15, ty = tid >> 4;
    const int bx = blockIdx.x, by = blockIdx.y;
    const int arow = tid >> 2;
    const int acol = (tid & 3) << 2;
    const float* Ap = A + (size_t)((by << 6) + arow) * K + acol;
    const float* Bp = B + (size_t)((bx << 6) + arow) * K + acol;
    float acc[4][4] = {};
    for (int k0 = 0; k0 < K; k0 += 16) {
        float4 av = *(const float4*)Ap;
        float4 bv = *(const float4*)Bp;
        As[acol + 0][arow] = av.x;
        As[acol + 1][arow] = av.y;
        As[acol + 2][arow] = av.z;
        As[acol + 3][arow] = av.w;
        Bs[acol + 0][arow] = bv.x;
        Bs[acol + 1][arow] = bv.y;
        Bs[acol + 2][arow] = bv.z;
        Bs[acol + 3][arow] = bv.w;
        __syncthreads();
#pragma unroll
        for (int kk = 0; kk < 16; kk++) {
            float4 a = *(const float4*)&As[kk][ty << 2];
            float4 b = *(const float4*)&Bs[kk][tx << 2];
            acc[0][0] += a.x * b.x; acc[0][1] += a.x * b.y; acc[0][2] += a.x * b.z; acc[0][3] += a.x * b.w;
            acc[1][0] += a.y * b.x; acc[1][1] += a.y * b.y; acc[1][2] += a.y * b.z; acc[1][3] += a.y * b.w;
            acc[2][0] += a.z * b.x; acc[2][1] += a.z * b.y; acc[2][2] += a.z * b.z; acc[2][3] += a.z * b.w;
            acc[3][0] += a.w * b.x; acc[3][1] += a.w * b.y; acc[3][2] += a.w * b.z; acc[3][3] += a.w * b.w;
        }
        __syncthreads();
        Ap += 16;
        Bp += 16;
    }
    const int ccol = (bx << 6) + (tx << 2);
#pragma unroll
    for (int i = 0; i < 4; i++) {
        const int row = (by << 6) + (ty << 2) + i;
        float4 o;
        o.x = acc[i][0] * scale;
        o.y = acc[i][1] * scale;
        o.z = acc[i][2] * scale;
        o.w = acc[i][3] * scale;
        *(float4*)&C[(size_t)row * N + ccol] = o;
    }
}

// ---------------- causal softmax over rows of sc[S,S] ---------------------
__global__ __launch_bounds__(256) void softmax_causal_k(float* __restrict__ sc)
{
    const int i = blockIdx.x;
    float* row = sc + (size_t)i * SEQ;
    const int n = i + 1;
    const int tid = threadIdx.x;
    __shared__ float red[4];
    float m = -3.402823466e38f;
    for (int j = tid; j < n; j += 256) m = fmaxf(m, row[j]);
#pragma unroll
    for (int o = 32; o > 0; o >>= 1) m = fmaxf(m, __shfl_down(m, o, 64));
    if ((tid & 63) == 0) red[tid >> 6] = m;
    __syncthreads();
    m = fmaxf(fmaxf(red[0], red[1]), fmaxf(red[2], red[3]));
    __syncthreads();
    float ssum = 0.f;
    for (int j = tid; j < n; j += 256) {
        float e = expf(row[j] - m);
        row[j] = e;
        ssum += e;
    }
#pragma unroll
    for (int o = 32; o > 0; o >>= 1) ssum += __shfl_down(ssum, o, 64);
    if ((tid & 63) == 0) red[tid >> 6] = ssum;
    __syncthreads();
    const float inv = 1.0f / (red[0] + red[1] + red[2] + red[3]);
    for (int j = tid; j < n; j += 256) row[j] *= inv;
    for (int j = n + tid; j < SEQ; j += 256) row[j] = 0.f;
}

// ---------------- out = LN(z + res) * g + b  (width DIM=512) --------------
__global__ __launch_bounds__(256) void add_ln_k(
    const float* __restrict__ z, const float* __restrict__ res,
    const float* __restrict__ g, const float* __restrict__ b,
    float* __restrict__ outp)
{
    const int row = blockIdx.x;
    const int tid = threadIdx.x;
    __shared__ float red[4];
    const size_t base = (size_t)row * DIM;
    const float v0 = z[base + tid] + res[base + tid];
    const float v1 = z[base + tid + 256] + res[base + tid + 256];
    float s = v0 + v1;
#pragma unroll
    for (int o = 32; o > 0; o >>= 1) s += __shfl_down(s, o, 64);
    if ((tid & 63) == 0) red[tid >> 6] = s;
    __syncthreads();
    const float mean = (red[0] + red[1] + red[2] + red[3]) * (1.0f / DIM);
    __syncthreads();
    const float d0 = v0 - mean, d1 = v1 - mean;
    float vs = d0 * d0 + d1 * d1;
#pragma unroll
    for (int o = 32; o > 0; o >>= 1) vs += __shfl_down(vs, o, 64);
    if ((tid & 63) == 0) red[tid >> 6] = vs;
    __syncthreads();
    const float var = (red[0] + red[1] + red[2] + red[3]) * (1.0f / DIM);
    const float inv = 1.0f / sqrtf(var + LNEPS);
    outp[base + tid]       = d0 * inv * g[tid] + b[tid];
    outp[base + tid + 256] = d1 * inv * g[tid + 256] + b[tid + 256];
}

// ---------------- final row softmax over VOCAB ----------------------------
__global__ __launch_bounds__(256) void softmax_rows_k(float* __restrict__ p)
{
    const int i = blockIdx.x;
    float* row = p + (size_t)i * VOCAB;
    const int tid = threadIdx.x;
    __shared__ float red[4];
    float m = -3.402823466e38f;
    for (int j = tid; j < VOCAB; j += 256) m = fmaxf(m, row[j]);
#pragma unroll
    for (int o = 32; o > 0; o >>= 1) m = fmaxf(m, __shfl_down(m, o, 64));
    if ((tid & 63) == 0) red[tid >> 6] = m;
    __syncthreads();
    m = fmaxf(fmaxf(red[0], red[1]), fmaxf(red[2], red[3]));
    __syncthreads();
    float ssum = 0.f;
    for (int j = tid; j < VOCAB; j += 256) {
        float e = expf(row[j] - m);
        row[j] = e;
        ssum += e;
    }
#pragma unroll
    for (int o = 32; o > 0; o >>= 1) ssum += __shfl_down(ssum, o, 64);
    if ((tid & 63) == 0) red[tid >> 6] = ssum;
    __syncthreads();
    const float inv = 1.0f / (red[0] + red[1] + red[2] + red[3]);
    for (int j = tid; j < VOCAB; j += 256) row[j] *= inv;
}

extern "C" void kernel_launch(void* const* d_in, const int* in_sizes, int n_in,
                              void* d_out, int out_size, void* d_ws, size_t ws_size,
                              hipStream_t stream)
{
    const float* x   = (const float*)d_in[0];
    const float* Wq  = (const float*)d_in[1];
    const float* bq  = (const float*)d_in[2];
    const float* Wk  = (const float*)d_in[3];
    const float* bk  = (const float*)d_in[4];
    const float* Wv  = (const float*)d_in[5];
    const float* bv  = (const float*)d_in[6];
    const float* Wp  = (const float*)d_in[7];
    const float* bp  = (const float*)d_in[8];
    const float* g1  = (const float*)d_in[9];
    const float* be1 = (const float*)d_in[10];
    const float* W1  = (const float*)d_in[11];
    const float* b1  = (const float*)d_in[12];
    const float* W2  = (const float*)d_in[13];
    const float* b2  = (const float*)d_in[14];
    const float* g2  = (const float*)d_in[15];
    const float* be2 = (const float*)d_in[16];
    const float* Wf  = (const float*)d_in[17];
    const float* bf  = (const float*)d_in[18];
    float* out = (float*)d_out;

    char* ws = (char*)d_ws;
    auto alloc = [&](size_t nfloats) {
        float* p = (float*)ws;
        ws += nfloats * sizeof(float);
        return p;
    };
    float* x0 = alloc((size_t)SEQ * DIM);   // current x (layer in/out)
    float* x1 = alloc((size_t)SEQ * DIM);   // post-attention x
    float* qb = alloc((size_t)SEQ * FDIM);  // q  (reused as z2)
    float* kb = alloc((size_t)SEQ * FDIM);  // k
    float* vb = alloc((size_t)SEQ * FDIM);  // v
    float* zb = alloc((size_t)SEQ * FDIM);  // att@v out / FFN out
    float* sc = alloc((size_t)SEQ * SEQ);   // scores / FFN hidden (same size)

    hipMemcpyAsync(x0, x, (size_t)SEQ * DIM * sizeof(float),
                   hipMemcpyDeviceToDevice, stream);

    const float scale = 1.0f / sqrtf((float)FDIM);
    dim3 blk(256);

    for (int l = 0; l < NLAYER; l++) {
        const float* Wq_l  = Wq  + (size_t)l * DIM * FDIM;
        const float* bq_l  = bq  + (size_t)l * FDIM;
        const float* Wk_l  = Wk  + (size_t)l * DIM * FDIM;
        const float* bk_l  = bk  + (size_t)l * FDIM;
        const float* Wv_l  = Wv  + (size_t)l * DIM * FDIM;
        const float* bv_l  = bv  + (size_t)l * FDIM;
        const float* Wp_l  = Wp  + (size_t)l * FDIM * FDIM;
        const float* bp_l  = bp  + (size_t)l * FDIM;
        const float* g1_l  = g1  + (size_t)l * FDIM;
        const float* be1_l = be1 + (size_t)l * FDIM;
        const float* W1_l  = W1  + (size_t)l * FDIM * HDIM;
        const float* b1_l  = b1  + (size_t)l * HDIM;
        const float* W2_l  = W2  + (size_t)l * HDIM * DIM;
        const float* b2_l  = b2  + (size_t)l * DIM;
        const float* g2_l  = g2  + (size_t)l * DIM;
        const float* be2_l = be2 + (size_t)l * DIM;

        // q, k, v
        gemm_nn_k<<<dim3(FDIM / 64, SEQ / 64), blk, 0, stream>>>(x0, Wq_l, bq_l, qb, SEQ, FDIM, DIM);
        gemm_nn_k<<<dim3(FDIM / 64, SEQ / 64), blk, 0, stream>>>(x0, Wk_l, bk_l, kb, SEQ, FDIM, DIM);
        gemm_nn_k<<<dim3(FDIM / 64, SEQ / 64), blk, 0, stream>>>(x0, Wv_l, bv_l, vb, SEQ, FDIM, DIM);
        // scores = scale * q @ k^T ; causal softmax
        gemm_nt_k<<<dim3(SEQ / 64, SEQ / 64), blk, 0, stream>>>(qb, kb, sc, SEQ, SEQ, FDIM, scale);
        softmax_causal_k<<<dim3(SEQ), blk, 0, stream>>>(sc);
        // z = att @ v ; z2 = z @ Wp + bp (z2 into qb, q no longer needed)
        gemm_nn_k<<<dim3(FDIM / 64, SEQ / 64), blk, 0, stream>>>(sc, vb, nullptr, zb, SEQ, FDIM, SEQ);
        gemm_nn_k<<<dim3(FDIM / 64, SEQ / 64), blk, 0, stream>>>(zb, Wp_l, bp_l, qb, SEQ, FDIM, FDIM);
        // x1 = LN(z2 + x0)
        add_ln_k<<<dim3(SEQ), blk, 0, stream>>>(qb, x0, g1_l, be1_l, x1);
        // FFN: h = x1 @ W1 + b1 (into sc, same size S*4F); h2 = h @ W2 + b2
        gemm_nn_k<<<dim3(HDIM / 64, SEQ / 64), blk, 0, stream>>>(x1, W1_l, b1_l, sc, SEQ, HDIM, FDIM);
        gemm_nn_k<<<dim3(DIM / 64, SEQ / 64), blk, 0, stream>>>(sc, W2_l, b2_l, zb, SEQ, DIM, HDIM);
        // x0 = LN(h2 + x1)
        add_ln_k<<<dim3(SEQ), blk, 0, stream>>>(zb, x1, g2_l, be2_l, x0);
    }

    // logits = x0 @ Wf + bf -> d_out ; row softmax in place
    gemm_nn_k<<<dim3(VOCAB / 64, SEQ / 64), blk, 0, stream>>>(x0, Wf, bf, out, SEQ, VOCAB, DIM);
    softmax_rows_k<<<dim3(SEQ), blk, 0, stream>>>(out);
}

// Round 2
// 2377.833 us; speedup vs baseline: 1.7323x; 1.7323x over previous
//
#include <hip/hip_runtime.h>
#include <cmath>

#define SEQ 2048
#define DIM 512
#define FDIM 512
#define HDIM 2048
#define VOCAB 32000
#define NLAYER 4
#define LNEPS 1e-5f

typedef unsigned short ushort_t;
typedef __attribute__((ext_vector_type(8))) short short8;
typedef __attribute__((ext_vector_type(4))) float f32x4;

// ---------- bf16 helpers (RNE) ----------
__device__ __forceinline__ ushort_t f2bf(float x) {
    union { float f; unsigned int u; } a; a.f = x;
    unsigned int r = a.u + 0x7fffu + ((a.u >> 16) & 1u);
    return (ushort_t)(r >> 16);
}
__device__ __forceinline__ float bf2f(ushort_t b) {
    union { unsigned int u; float f; } a; a.u = ((unsigned int)b) << 16; return a.f;
}

// ---------- async global->LDS 16B ----------
__device__ __forceinline__ void gload_lds16(const ushort_t* g, ushort_t* l) {
    __builtin_amdgcn_global_load_lds(
        (const __attribute__((address_space(1))) void*)g,
        (__attribute__((address_space(3))) void*)l, 16, 0, 0);
}

// =====================================================================
// GEMM: C[M][N](ldc) (+)= scale * A[M][K] @ B[N][K]^T   (bf16 hi/lo x3)
// A,B pre-split compact bf16. 128x128 tile, BK=32, 256 thr (4 waves),
// each wave a 64x64 quadrant = 4x4 tiles of 16x16x32 MFMA, 3 mfma/tile.
// splitk>1: partial-K slices atomicAdd into pre-zeroed C.
// =====================================================================
__global__ __launch_bounds__(256) void gemm_bf16x3_k(
    const ushort_t* __restrict__ Ah, const ushort_t* __restrict__ Al,
    const ushort_t* __restrict__ Bh, const ushort_t* __restrict__ Bl,
    const float* __restrict__ bias, float* __restrict__ C,
    int N, int K, int ldc, float scale, int splitk)
{
    __shared__ ushort_t lds[16384];        // 4 x 8KB: Ah | Al | Bh | Bl
    ushort_t* ldsAh = lds;
    ushort_t* ldsAl = lds + 4096;
    ushort_t* ldsBh = lds + 8192;
    ushort_t* ldsBl = lds + 12288;

    const int tid  = threadIdx.x;
    const int lane = tid & 63, wv = tid >> 6;
    const int wm = wv >> 1, wn = wv & 1;
    const int q = lane >> 4, mlo = lane & 15;
    const int tm = blockIdx.y << 7, tn = blockIdx.x << 7;
    const int ksteps = (K >> 5) / splitk;
    const int kbase  = blockIdx.z * ksteps * 32;

    f32x4 acc[4][4];
#pragma unroll
    for (int i = 0; i < 4; i++)
#pragma unroll
        for (int j = 0; j < 4; j++)
            acc[i][j] = (f32x4){0.f, 0.f, 0.f, 0.f};

    for (int ks = 0; ks < ksteps; ks++) {
        const int k0 = kbase + (ks << 5);
        // ---- stage: 512 16B-chunks per buffer; chunk c=(kb<<7)|i holds
        //      X[i][k0+kb*8 .. +8); lds offset = c*16B. Wave-uniform dst base.
#pragma unroll
        for (int r = 0; r < 2; r++) {
            const int c  = (r << 8) + (wv << 6) + lane;
            const int i  = c & 127, kb = c >> 7;
            const int lofs = ((r << 8) + (wv << 6)) << 3;   // ushort units
            const size_t aoff = (size_t)(tm + i) * K + k0 + (kb << 3);
            const size_t boff = (size_t)(tn + i) * K + k0 + (kb << 3);
            gload_lds16(Ah + aoff, ldsAh + lofs);
            gload_lds16(Al + aoff, ldsAl + lofs);
            gload_lds16(Bh + boff, ldsBh + lofs);
            gload_lds16(Bl + boff, ldsBl + lofs);
        }
        __syncthreads();   // drains vmcnt before any wave reads LDS

        short8 ah[4], al[4], bh[4], bl[4];
#pragma unroll
        for (int t = 0; t < 4; t++) {
            const int ma = ((q << 7) + (wm << 6) + (t << 4) + mlo) << 3;
            const int nb = ((q << 7) + (wn << 6) + (t << 4) + mlo) << 3;
            ah[t] = *(const short8*)&ldsAh[ma];
            al[t] = *(const short8*)&ldsAl[ma];
            bh[t] = *(const short8*)&ldsBh[nb];
            bl[t] = *(const short8*)&ldsBl[nb];
        }
#pragma unroll
        for (int i = 0; i < 4; i++)
#pragma unroll
            for (int j = 0; j < 4; j++) {
                acc[i][j] = __builtin_amdgcn_mfma_f32_16x16x32_bf16(ah[i], bh[j], acc[i][j], 0, 0, 0);
                acc[i][j] = __builtin_amdgcn_mfma_f32_16x16x32_bf16(ah[i], bl[j], acc[i][j], 0, 0, 0);
                acc[i][j] = __builtin_amdgcn_mfma_f32_16x16x32_bf16(al[i], bh[j], acc[i][j], 0, 0, 0);
            }
        __syncthreads();   // all waves done with LDS before next stage
    }

    // ---- epilogue: C/D layout col=lane&15, row=(lane>>4)*4+reg ----
    const bool addb = (bias != nullptr) && (blockIdx.z == 0);
#pragma unroll
    for (int ti = 0; ti < 4; ti++)
#pragma unroll
        for (int tj = 0; tj < 4; tj++) {
            const int col = tn + (wn << 6) + (tj << 4) + mlo;
            const float bb = addb ? bias[col] : 0.f;
#pragma unroll
            for (int r = 0; r < 4; r++) {
                const int row = tm + (wm << 6) + (ti << 4) + (q << 2) + r;
                const float v = acc[ti][tj][r] * scale + bb;
                if (splitk == 1) C[(size_t)row * ldc + col] = v;
                else atomicAdd(&C[(size_t)row * ldc + col], v);
            }
        }
}

// ---------- split fp32[R][C](ld) -> compact bf16 hi/lo [R][C] ----------
__global__ __launch_bounds__(128) void split_k(
    const float* __restrict__ src, int ld, int C,
    ushort_t* __restrict__ dh, ushort_t* __restrict__ dl)
{
    const int row = blockIdx.y;
    const int c4 = ((blockIdx.x << 7) + threadIdx.x) << 2;
    if (c4 >= C) return;
    const float4 v = *(const float4*)&src[(size_t)row * ld + c4];
    ushort_t h[4], l[4];
    const float f[4] = {v.x, v.y, v.z, v.w};
#pragma unroll
    for (int i = 0; i < 4; i++) {
        h[i] = f2bf(f[i]);
        l[i] = f2bf(f[i] - bf2f(h[i]));
    }
    *(ushort4*)&dh[(size_t)row * C + c4] = make_ushort4(h[0], h[1], h[2], h[3]);
    *(ushort4*)&dl[(size_t)row * C + c4] = make_ushort4(l[0], l[1], l[2], l[3]);
}

// ---------- transpose+split fp32[R][C](ld) -> bf16 hi/lo [C][R] ----------
__global__ __launch_bounds__(256) void tsplit_k(
    const float* __restrict__ src, int ld, int R,
    ushort_t* __restrict__ dh, ushort_t* __restrict__ dl)
{
    __shared__ float t[32][33];
    const int c = threadIdx.x & 31, r8 = threadIdx.x >> 5;
    const int bx = blockIdx.x, by = blockIdx.y;
#pragma unroll
    for (int i = 0; i < 4; i++) {
        const int r = (r8 << 2) + i;
        t[r][c] = src[(size_t)((by << 5) + r) * ld + (bx << 5) + c];
    }
    __syncthreads();
#pragma unroll
    for (int i = 0; i < 4; i++) {
        const int rr = (r8 << 2) + i;            // output row' = bx*32+rr
        const float v = t[c][rr];                // src[by*32+c][bx*32+rr]
        const ushort_t h = f2bf(v);
        const ushort_t l = f2bf(v - bf2f(h));
        const size_t o = (size_t)((bx << 5) + rr) * R + (by << 5) + c;
        dh[o] = h; dl[o] = l;
    }
}

// ---------- gather merged qkv bias [1536] ----------
__global__ void gather3_k(const float* a, const float* b, const float* c, float* d)
{
    const int i = blockIdx.x * 256 + threadIdx.x;
    if (i >= 1536) return;
    d[i] = (i < 512) ? a[i] : ((i < 1024) ? b[i - 512] : c[i - 1024]);
}

// ---------- causal softmax over rows of sc[S,S] ----------
__global__ __launch_bounds__(256) void softmax_causal_k(float* __restrict__ sc)
{
    const int i = blockIdx.x;
    float* row = sc + (size_t)i * SEQ;
    const int n = i + 1;
    const int tid = threadIdx.x;
    __shared__ float red[4];
    float m = -3.402823466e38f;
    for (int j = tid; j < n; j += 256) m = fmaxf(m, row[j]);
#pragma unroll
    for (int o = 32; o > 0; o >>= 1) m = fmaxf(m, __shfl_down(m, o, 64));
    if ((tid & 63) == 0) red[tid >> 6] = m;
    __syncthreads();
    m = fmaxf(fmaxf(red[0], red[1]), fmaxf(red[2], red[3]));
    __syncthreads();
    float ssum = 0.f;
    for (int j = tid; j < n; j += 256) {
        const float e = expf(row[j] - m);
        row[j] = e;
        ssum += e;
    }
#pragma unroll
    for (int o = 32; o > 0; o >>= 1) ssum += __shfl_down(ssum, o, 64);
    if ((tid & 63) == 0) red[tid >> 6] = ssum;
    __syncthreads();
    const float inv = 1.0f / (red[0] + red[1] + red[2] + red[3]);
    for (int j = tid; j < n; j += 256) row[j] *= inv;
    for (int j = n + tid; j < SEQ; j += 256) row[j] = 0.f;
}

// ---------- out = LN(z + res) * g + b  (width 512) ----------
__global__ __launch_bounds__(256) void add_ln_k(
    const float* __restrict__ z, const float* __restrict__ res,
    const float* __restrict__ g, const float* __restrict__ b,
    float* __restrict__ outp)
{
    const int row = blockIdx.x;
    const int tid = threadIdx.x;
    __shared__ float red[4];
    const size_t base = (size_t)row * DIM;
    const float v0 = z[base + tid] + res[base + tid];
    const float v1 = z[base + tid + 256] + res[base + tid + 256];
    float s = v0 + v1;
#pragma unroll
    for (int o = 32; o > 0; o >>= 1) s += __shfl_down(s, o, 64);
    if ((tid & 63) == 0) red[tid >> 6] = s;
    __syncthreads();
    const float mean = (red[0] + red[1] + red[2] + red[3]) * (1.0f / DIM);
    __syncthreads();
    const float d0 = v0 - mean, d1 = v1 - mean;
    float vs = d0 * d0 + d1 * d1;
#pragma unroll
    for (int o = 32; o > 0; o >>= 1) vs += __shfl_down(vs, o, 64);
    if ((tid & 63) == 0) red[tid >> 6] = vs;
    __syncthreads();
    const float var = (red[0] + red[1] + red[2] + red[3]) * (1.0f / DIM);
    const float inv = 1.0f / sqrtf(var + LNEPS);
    outp[base + tid]       = d0 * inv * g[tid] + b[tid];
    outp[base + tid + 256] = d1 * inv * g[tid + 256] + b[tid + 256];
}

// ---------- final row softmax over VOCAB ----------
__global__ __launch_bounds__(256) void softmax_rows_k(float* __restrict__ p)
{
    const int i = blockIdx.x;
    float* row = p + (size_t)i * VOCAB;
    const int tid = threadIdx.x;
    __shared__ float red[4];
    float m = -3.402823466e38f;
    for (int j = tid; j < VOCAB; j += 256) m = fmaxf(m, row[j]);
#pragma unroll
    for (int o = 32; o > 0; o >>= 1) m = fmaxf(m, __shfl_down(m, o, 64));
    if ((tid & 63) == 0) red[tid >> 6] = m;
    __syncthreads();
    m = fmaxf(fmaxf(red[0], red[1]), fmaxf(red[2], red[3]));
    __syncthreads();
    float ssum = 0.f;
    for (int j = tid; j < VOCAB; j += 256) {
        const float e = expf(row[j] - m);
        row[j] = e;
        ssum += e;
    }
#pragma unroll
    for (int o = 32; o > 0; o >>= 1) ssum += __shfl_down(ssum, o, 64);
    if ((tid & 63) == 0) red[tid >> 6] = ssum;
    __syncthreads();
    const float inv = 1.0f / (red[0] + red[1] + red[2] + red[3]);
    for (int j = tid; j < VOCAB; j += 256) row[j] *= inv;
}

extern "C" void kernel_launch(void* const* d_in, const int* in_sizes, int n_in,
                              void* d_out, int out_size, void* d_ws, size_t ws_size,
                              hipStream_t stream)
{
    const float* x   = (const float*)d_in[0];
    const float* Wq  = (const float*)d_in[1];
    const float* bq  = (const float*)d_in[2];
    const float* Wk  = (const float*)d_in[3];
    const float* bk  = (const float*)d_in[4];
    const float* Wv  = (const float*)d_in[5];
    const float* bv  = (const float*)d_in[6];
    const float* Wp  = (const float*)d_in[7];
    const float* bp  = (const float*)d_in[8];
    const float* g1  = (const float*)d_in[9];
    const float* be1 = (const float*)d_in[10];
    const float* W1  = (const float*)d_in[11];
    const float* b1  = (const float*)d_in[12];
    const float* W2  = (const float*)d_in[13];
    const float* b2  = (const float*)d_in[14];
    const float* g2  = (const float*)d_in[15];
    const float* be2 = (const float*)d_in[16];
    const float* Wf  = (const float*)d_in[17];
    const float* bf  = (const float*)d_in[18];
    float* out = (float*)d_out;

    // ---- workspace carve (aligned 256B) ----
    char* ws = (char*)d_ws;
    auto alloc = [&](size_t bytes) {
        void* p = ws;
        ws += (bytes + 255) & ~(size_t)255;
        return p;
    };
    float*    x0   = (float*)alloc((size_t)SEQ * DIM * 4);        // 4 MB
    float*    x1   = (float*)alloc((size_t)SEQ * DIM * 4);        // 4 MB
    float*    qkv  = (float*)alloc((size_t)SEQ * 1536 * 4);       // 12 MB
    float*    zb   = (float*)alloc((size_t)SEQ * FDIM * 4);       // 4 MB
    float*    z2   = (float*)alloc((size_t)SEQ * FDIM * 4);       // 4 MB
    float*    sc   = (float*)alloc((size_t)SEQ * SEQ * 4);        // 16 MB
    ushort_t* Ah   = (ushort_t*)alloc((size_t)SEQ * SEQ * 2);     // 8 MB
    ushort_t* Al   = (ushort_t*)alloc((size_t)SEQ * SEQ * 2);     // 8 MB
    ushort_t* Bh   = (ushort_t*)alloc((size_t)8192 * 512 * 2);    // 8.4 MB
    ushort_t* Bl   = (ushort_t*)alloc((size_t)8192 * 512 * 2);    // 8.4 MB
    float*    bqkv = (float*)alloc(1536 * 4);

    hipMemcpyAsync(x0, x, (size_t)SEQ * DIM * 4, hipMemcpyDeviceToDevice, stream);

    const float att_scale = 1.0f / sqrtf((float)FDIM);
    const dim3 b256(256), b128(128);

    auto split = [&](const float* src, int ld, int R, int C, ushort_t* dh, ushort_t* dl) {
        split_k<<<dim3((C / 4 + 127) / 128, R), b128, 0, stream>>>(src, ld, C, dh, dl);
    };
    auto tsplit = [&](const float* src, int ld, int R, int C, ushort_t* dh, ushort_t* dl) {
        tsplit_k<<<dim3(C / 32, R / 32), b256, 0, stream>>>(src, ld, R, dh, dl);
    };
    auto gemm = [&](const ushort_t* ah, const ushort_t* al,
                    const ushort_t* bh, const ushort_t* bl,
                    const float* bias, float* C, int N, int K, int ldc,
                    float scale, int splitk) {
        if (splitk > 1)
            hipMemsetAsync(C, 0, (size_t)SEQ * ldc * 4, stream);
        gemm_bf16x3_k<<<dim3(N / 128, SEQ / 128, splitk), b256, 0, stream>>>(
            ah, al, bh, bl, bias, C, N, K, ldc, scale, splitk);
    };

    for (int l = 0; l < NLAYER; l++) {
        const float* Wq_l = Wq + (size_t)l * DIM * FDIM;
        const float* Wk_l = Wk + (size_t)l * DIM * FDIM;
        const float* Wv_l = Wv + (size_t)l * DIM * FDIM;
        const float* Wp_l = Wp + (size_t)l * FDIM * FDIM;
        const float* W1_l = W1 + (size_t)l * FDIM * HDIM;
        const float* W2_l = W2 + (size_t)l * HDIM * DIM;

        // merged qkv: B = [Wq^T; Wk^T; Wv^T]  (1536 x 512)
        tsplit(Wq_l, FDIM, DIM, FDIM, Bh, Bl);
        tsplit(Wk_l, FDIM, DIM, FDIM, Bh + (size_t)512 * 512, Bl + (size_t)512 * 512);
        tsplit(Wv_l, FDIM, DIM, FDIM, Bh + (size_t)1024 * 512, Bl + (size_t)1024 * 512);
        gather3_k<<<dim3(6), b256, 0, stream>>>(bq + l * FDIM, bk + l * FDIM, bv + l * FDIM, bqkv);
        split(x0, DIM, SEQ, DIM, Ah, Al);
        gemm(Ah, Al, Bh, Bl, bqkv, qkv, 1536, DIM, 1536, 1.0f, 2);

        // scores = scale * q @ k^T ; causal softmax
        split(qkv, 1536, SEQ, FDIM, Ah, Al);                 // q
        split(qkv + 512, 1536, SEQ, FDIM, Bh, Bl);           // k
        gemm(Ah, Al, Bh, Bl, nullptr, sc, SEQ, FDIM, SEQ, att_scale, 2);
        softmax_causal_k<<<dim3(SEQ), b256, 0, stream>>>(sc);

        // z = att @ v
        tsplit(qkv + 1024, 1536, SEQ, FDIM, Bh, Bl);         // v^T [512][2048]
        split(sc, SEQ, SEQ, SEQ, Ah, Al);                    // att
        gemm(Ah, Al, Bh, Bl, nullptr, zb, FDIM, SEQ, FDIM, 1.0f, 4);

        // z2 = z @ Wp + bp
        split(zb, FDIM, SEQ, FDIM, Ah, Al);
        tsplit(Wp_l, FDIM, FDIM, FDIM, Bh, Bl);
        gemm(Ah, Al, Bh, Bl, bp + l * FDIM, z2, FDIM, FDIM, FDIM, 1.0f, 4);

        // x1 = LN(z2 + x0)
        add_ln_k<<<dim3(SEQ), b256, 0, stream>>>(z2, x0, g1 + l * FDIM, be1 + l * FDIM, x1);

        // h = x1 @ W1 + b1  (into sc)
        split(x1, FDIM, SEQ, FDIM, Ah, Al);
        tsplit(W1_l, HDIM, FDIM, HDIM, Bh, Bl);              // [2048][512]
        gemm(Ah, Al, Bh, Bl, b1 + l * HDIM, sc, HDIM, FDIM, HDIM, 1.0f, 2);

        // h2 = h @ W2 + b2
        split(sc, HDIM, SEQ, HDIM, Ah, Al);
        tsplit(W2_l, DIM, HDIM, DIM, Bh, Bl);                // [512][2048]
        gemm(Ah, Al, Bh, Bl, b2 + l * DIM, z2, DIM, HDIM, DIM, 1.0f, 4);

        // x0 = LN(h2 + x1)
        add_ln_k<<<dim3(SEQ), b256, 0, stream>>>(z2, x1, g2 + l * DIM, be2 + l * DIM, x0);
    }

    // logits = x0 @ Wf + bf, chunked over vocab columns; then row softmax
    split(x0, DIM, SEQ, DIM, Ah, Al);
    for (int n0 = 0; n0 < VOCAB; n0 += 8192) {
        const int nc = (VOCAB - n0 < 8192) ? (VOCAB - n0) : 8192;   // 8192/7424
        tsplit(Wf + n0, VOCAB, DIM, nc, Bh, Bl);                    // [nc][512]
        gemm_bf16x3_k<<<dim3(nc / 128, SEQ / 128, 1), b256, 0, stream>>>(
            Ah, Al, Bh, Bl, bf + n0, out + n0, nc, DIM, VOCAB, 1.0f, 1);
    }
    softmax_rows_k<<<dim3(SEQ), b256, 0, stream>>>(out);
}